// Round 2
// baseline (1408.393 us; speedup 1.0000x reference)
//
#include <hip/hip_runtime.h>

#define DD 128

typedef __attribute__((ext_vector_type(8))) short bf16x8;
typedef __attribute__((ext_vector_type(4))) short bf16x4;
typedef __attribute__((ext_vector_type(4))) float f32x4;

__device__ __forceinline__ unsigned short f2bf(float f) {
  union { float f; unsigned u; } v; v.f = f;
  unsigned u = v.u;
  return (unsigned short)((u + 0x7FFFu + ((u >> 16) & 1u)) >> 16);
}

__device__ __forceinline__ bf16x8 pack8(f32x4 a, f32x4 b) {
  bf16x8 r;
  r[0] = (short)f2bf(a.x); r[1] = (short)f2bf(a.y);
  r[2] = (short)f2bf(a.z); r[3] = (short)f2bf(a.w);
  r[4] = (short)f2bf(b.x); r[5] = (short)f2bf(b.y);
  r[6] = (short)f2bf(b.z); r[7] = (short)f2bf(b.w);
  return r;
}

// edge_index may arrive as int32 or int64 (reference declares int64; harness
// convention says int32). Detect: int64 viewed as int32 has zero high words at
// odd slots. Values are random in [0,50000) so 4 zeros in a row ~ impossible
// for genuine int32 data.
__device__ __forceinline__ bool idx_is64(const int* p) {
  return (p[1] | p[3] | p[5] | p[7]) == 0;
}
__device__ __forceinline__ int ld_idx(const int* p, long long i, bool is64) {
  return is64 ? (int)((const long long*)p)[i] : p[i];
}

__global__ void k_count(const int* __restrict__ idx, int* __restrict__ cnt, int E) {
  int e = blockIdx.x * blockDim.x + threadIdx.x;
  if (e >= E) return;
  bool is64 = idx_is64(idx);
  int d = ld_idx(idx, (long long)E + e, is64);
  atomicAdd(&cnt[d], 1);
}

__global__ __launch_bounds__(1024) void k_scan(const int* __restrict__ cnt,
    int* __restrict__ row_start, int* __restrict__ cursor, int N) {
  __shared__ int part[1024];
  int t = threadIdx.x;
  int chunk = (N + 1023) >> 10;
  int lo = t * chunk, hi = lo + chunk; if (hi > N) hi = N; if (lo > N) lo = N;
  int s = 0;
  for (int i = lo; i < hi; ++i) s += cnt[i];
  part[t] = s;
  __syncthreads();
  for (int off = 1; off < 1024; off <<= 1) {
    int v = (t >= off) ? part[t - off] : 0;
    __syncthreads();
    part[t] += v;
    __syncthreads();
  }
  int run = (t == 0) ? 0 : part[t - 1];
  for (int i = lo; i < hi; ++i) {
    row_start[i] = run; cursor[i] = run; run += cnt[i];
  }
  if (t == 1023) row_start[N] = part[1023];
}

__global__ void k_fill(const int* __restrict__ idx, int* __restrict__ cursor,
                       int* __restrict__ edge_of, int E) {
  int e = blockIdx.x * blockDim.x + threadIdx.x;
  if (e >= E) return;
  bool is64 = idx_is64(idx);
  int d = ld_idx(idx, (long long)E + e, is64);
  int pos = atomicAdd(&cursor[d], 1);
  edge_of[pos] = e;
}

// segment-mean of x[src] * ea over edges of each node. block = node.
__global__ __launch_bounds__(128) void k_agg(const float* __restrict__ x,
    const float* __restrict__ ea, const int* __restrict__ idx,
    const int* __restrict__ row_start, const int* __restrict__ edge_of,
    float* __restrict__ aggt, int E) {
  int n = blockIdx.x;
  int d = threadIdx.x;
  bool is64 = idx_is64(idx);
  int s0 = row_start[n], s1 = row_start[n + 1];
  float s = 0.f;
  for (int k = s0; k < s1; ++k) {
    int e = edge_of[k];
    int sn = ld_idx(idx, e, is64);
    s += x[(size_t)sn * DD + d] * ea[(size_t)e * DD + d];
  }
  float inv = (s1 > s0) ? 1.0f / (float)(s1 - s0) : 0.0f;
  aggt[(size_t)n * DD + d] = s * inv;
}

// ea_out[e][f] = sum_d ea_in[e][d] * W[f][d] + bias[f]  (in-place safe per-row)
__global__ __launch_bounds__(256) void k_rel(const float* __restrict__ ea_in,
    float* __restrict__ ea_out, const float* __restrict__ W,
    const float* __restrict__ bias, int ntiles) {
  __shared__ short Wl[DD * DD];
  for (int q = threadIdx.x; q < DD * DD / 4; q += 256) {
    int off = q * 4;
    int f = off >> 7, d = off & 127;
    f32x4 w = *(const f32x4*)(W + off);
    unsigned byte = ((unsigned)(f * 256 + d * 2)) ^ (unsigned)((f & 7) << 4);
    bf16x4 s4;
    s4[0] = (short)f2bf(w.x); s4[1] = (short)f2bf(w.y);
    s4[2] = (short)f2bf(w.z); s4[3] = (short)f2bf(w.w);
    *(bf16x4*)((char*)Wl + byte) = s4;
  }
  __syncthreads();
  int wave = threadIdx.x >> 6, lane = threadIdx.x & 63;
  int r = lane & 15, g = lane >> 4;
  for (int tile = blockIdx.x * 4 + wave; tile < ntiles; tile += gridDim.x * 4) {
    const float* rowp = ea_in + (size_t)(tile * 16 + r) * DD;
    bf16x8 a[4];
#pragma unroll
    for (int ks = 0; ks < 4; ++ks) {
      const float* p = rowp + ks * 32 + g * 8;
      a[ks] = pack8(*(const f32x4*)p, *(const f32x4*)(p + 4));
    }
    f32x4 acc[8];
#pragma unroll
    for (int ct = 0; ct < 8; ++ct) acc[ct] = (f32x4){0.f, 0.f, 0.f, 0.f};
#pragma unroll
    for (int ct = 0; ct < 8; ++ct) {
      int f = ct * 16 + r;
      unsigned base = (unsigned)(f * 256);
      unsigned sw = (unsigned)((f & 7) << 4);
#pragma unroll
      for (int ks = 0; ks < 4; ++ks) {
        unsigned byte = (base + (unsigned)(ks * 64 + g * 16)) ^ sw;
        bf16x8 b = *(const bf16x8*)((const char*)Wl + byte);
        acc[ct] = __builtin_amdgcn_mfma_f32_16x16x32_bf16(a[ks], b, acc[ct], 0, 0, 0);
      }
    }
    float* ob = ea_out + (size_t)tile * 16 * DD;
#pragma unroll
    for (int ct = 0; ct < 8; ++ct) {
      int col = ct * 16 + r;
      float bv = bias[col];
#pragma unroll
      for (int j = 0; j < 4; ++j) {
        ob[(size_t)(g * 4 + j) * DD + col] = acc[ct][j] + bv;
      }
    }
  }
}

// xn = aggt @ W_in^T + x @ W_self^T + b_self + (deg>0)*b_in ; optional BN stats
__global__ __launch_bounds__(256) void k_node(const float* __restrict__ aggt,
    const float* __restrict__ xc, const float* __restrict__ W_in,
    const float* __restrict__ W_self, const float* __restrict__ b_in,
    const float* __restrict__ b_self, const int* __restrict__ cnt,
    float* __restrict__ xn, float* __restrict__ gsum, float* __restrict__ gssq,
    int do_stats, int ntiles) {
  __shared__ short Wl[DD * 256];   // [f][k] k<128:W_in, k>=128:W_self (bf16, swizzled)
  for (int q = threadIdx.x; q < DD * 256 / 4; q += 256) {
    int off = q * 4;
    int f = off >> 8, k = off & 255;
    f32x4 w = (k < 128) ? *(const f32x4*)(W_in + f * 128 + k)
                        : *(const f32x4*)(W_self + f * 128 + (k - 128));
    unsigned byte = ((unsigned)(f * 512 + k * 2)) ^ (unsigned)((f & 7) << 4);
    bf16x4 s4;
    s4[0] = (short)f2bf(w.x); s4[1] = (short)f2bf(w.y);
    s4[2] = (short)f2bf(w.z); s4[3] = (short)f2bf(w.w);
    *(bf16x4*)((char*)Wl + byte) = s4;
  }
  __syncthreads();
  int wave = threadIdx.x >> 6, lane = threadIdx.x & 63;
  int tile = blockIdx.x * 4 + wave;
  if (tile >= ntiles) return;
  int r = lane & 15, g = lane >> 4;
  const float* arow = aggt + (size_t)(tile * 16 + r) * DD;
  const float* xrow = xc + (size_t)(tile * 16 + r) * DD;
  bf16x8 a[8];
#pragma unroll
  for (int ks = 0; ks < 8; ++ks) {
    const float* p = (ks < 4) ? (arow + ks * 32 + g * 8)
                              : (xrow + (ks - 4) * 32 + g * 8);
    a[ks] = pack8(*(const f32x4*)p, *(const f32x4*)(p + 4));
  }
  f32x4 acc[8];
#pragma unroll
  for (int ct = 0; ct < 8; ++ct) acc[ct] = (f32x4){0.f, 0.f, 0.f, 0.f};
#pragma unroll
  for (int ct = 0; ct < 8; ++ct) {
    int f = ct * 16 + r;
    unsigned base = (unsigned)(f * 512);
    unsigned sw = (unsigned)((f & 7) << 4);
#pragma unroll
    for (int ks = 0; ks < 8; ++ks) {
      unsigned byte = (base + (unsigned)(ks * 64 + g * 16)) ^ sw;
      bf16x8 b = *(const bf16x8*)((const char*)Wl + byte);
      acc[ct] = __builtin_amdgcn_mfma_f32_16x16x32_bf16(a[ks], b, acc[ct], 0, 0, 0);
    }
  }
  int nbase = tile * 16;
  float degmask[4];
#pragma unroll
  for (int j = 0; j < 4; ++j)
    degmask[j] = (cnt[nbase + g * 4 + j] > 0) ? 1.0f : 0.0f;
#pragma unroll
  for (int ct = 0; ct < 8; ++ct) {
    int col = ct * 16 + r;
    float bi = b_in[col], bs = b_self[col];
    float s = 0.f, s2 = 0.f;
#pragma unroll
    for (int j = 0; j < 4; ++j) {
      float v = acc[ct][j] + bs + bi * degmask[j];
      xn[(size_t)(nbase + g * 4 + j) * DD + col] = v;
      s += v; s2 += v * v;
    }
    if (do_stats) {
      s += __shfl_xor(s, 16);  s += __shfl_xor(s, 32);
      s2 += __shfl_xor(s2, 16); s2 += __shfl_xor(s2, 32);
      if (g == 0) { atomicAdd(&gsum[col], s); atomicAdd(&gssq[col], s2); }
    }
  }
}

__global__ void k_bnfin(const float* __restrict__ gsum, const float* __restrict__ gssq,
    const float* __restrict__ gamma, const float* __restrict__ beta,
    float* __restrict__ scale, float* __restrict__ shift, int N) {
  int d = threadIdx.x;
  float mu = gsum[d] / (float)N;
  float var = gssq[d] / (float)N - mu * mu;
  float rs = rsqrtf(var + 1e-5f);
  float sc = rs * gamma[d];
  scale[d] = sc;
  shift[d] = beta[d] - mu * sc;
}

__global__ void k_bnrelu(float* __restrict__ x, const float* __restrict__ scale,
                         const float* __restrict__ shift, int total4) {
  int i = blockIdx.x * blockDim.x + threadIdx.x;
  if (i >= total4) return;
  f32x4 v = ((f32x4*)x)[i];
  int d0 = (i * 4) & 127;
  v.x = fmaxf(v.x * scale[d0] + shift[d0], 0.f);
  v.y = fmaxf(v.y * scale[d0 + 1] + shift[d0 + 1], 0.f);
  v.z = fmaxf(v.z * scale[d0 + 2] + shift[d0 + 2], 0.f);
  v.w = fmaxf(v.w * scale[d0 + 3] + shift[d0 + 3], 0.f);
  ((f32x4*)x)[i] = v;
}

static inline size_t alignup(size_t v, size_t a) { return (v + a - 1) & ~(a - 1); }

extern "C" void kernel_launch(void* const* d_in, const int* in_sizes, int n_in,
                              void* d_out, int out_size, void* d_ws, size_t ws_size,
                              hipStream_t stream) {
  const float* x0     = (const float*)d_in[0];
  const float* ea0    = (const float*)d_in[1];
  const float* w_self = (const float*)d_in[2];
  const float* b_self = (const float*)d_in[3];
  const float* w_in   = (const float*)d_in[4];
  const float* b_in   = (const float*)d_in[5];
  const float* w_rel  = (const float*)d_in[6];
  const float* b_rel  = (const float*)d_in[7];
  const float* gamma  = (const float*)d_in[8];
  const float* beta   = (const float*)d_in[9];
  const int*   idx    = (const int*)d_in[10];

  const int N = in_sizes[0] / DD;
  const int E = in_sizes[1] / DD;

  char* w = (char*)d_ws;
  size_t off = 0;
  int* cnt       = (int*)(w + off); off = alignup(off + (size_t)N * 4, 256);
  int* row_start = (int*)(w + off); off = alignup(off + (size_t)(N + 1) * 4, 256);
  int* cursor    = (int*)(w + off); off = alignup(off + (size_t)N * 4, 256);
  int* edge_of   = (int*)(w + off); off = alignup(off + (size_t)E * 4, 256);
  float* gsum    = (float*)(w + off); off = alignup(off + 128 * 4, 256);
  float* gssq    = (float*)(w + off); off = alignup(off + 128 * 4, 256);
  float* scale   = (float*)(w + off); off = alignup(off + 128 * 4, 256);
  float* shift   = (float*)(w + off); off = alignup(off + 128 * 4, 256);
  float* aggt    = (float*)(w + off); off = alignup(off + (size_t)N * DD * 4, 256);
  float* xbufB   = (float*)(w + off); off = alignup(off + (size_t)N * DD * 4, 256);
  (void)ws_size; (void)n_in; (void)out_size;

  float* out_x  = (float*)d_out;
  float* out_ea = out_x + (size_t)N * DD;

  // ---- CSR build (per launch; depends only on edge_index) ----
  (void)hipMemsetAsync(cnt, 0, (size_t)N * 4, stream);
  int ethreads = 256, eblocks = (E + ethreads - 1) / ethreads;
  k_count<<<eblocks, ethreads, 0, stream>>>(idx, cnt, E);
  k_scan<<<1, 1024, 0, stream>>>(cnt, row_start, cursor, N);
  k_fill<<<eblocks, ethreads, 0, stream>>>(idx, cursor, edge_of, E);

  const int ntN = N / 16;           // 3125 (N divisible by 16)
  const int ntE = E / 16;           // 40000
  const int nodeBlocks = (ntN + 3) / 4;
  const int relBlocks = 2048;

  const float* xc = x0;
  const float* eac = ea0;

  for (int i = 0; i < 3; ++i) {
    float* xn  = (i == 0) ? out_x : (i == 1) ? xbufB : out_x;
    float* ean = out_ea;            // layer0: ea0 -> out_ea; then in-place
    int do_stats = (i < 2) ? 1 : 0;

    k_agg<<<N, 128, 0, stream>>>(xc, eac, idx, row_start, edge_of, aggt, E);
    if (do_stats) {
      (void)hipMemsetAsync(gsum, 0, 128 * 4, stream);
      (void)hipMemsetAsync(gssq, 0, 128 * 4, stream);
    }
    k_node<<<nodeBlocks, 256, 0, stream>>>(aggt, xc,
        w_in + (size_t)i * DD * DD, w_self + (size_t)i * DD * DD,
        b_in + (size_t)i * DD, b_self + (size_t)i * DD,
        cnt, xn, gsum, gssq, do_stats, ntN);
    k_rel<<<relBlocks, 256, 0, stream>>>(eac, ean,
        w_rel + (size_t)i * DD * DD, b_rel + (size_t)i * DD, ntE);
    if (do_stats) {
      k_bnfin<<<1, 128, 0, stream>>>(gsum, gssq, gamma + (size_t)i * DD,
                                     beta + (size_t)i * DD, scale, shift, N);
      k_bnrelu<<<((size_t)N * DD / 4 + 255) / 256, 256, 0, stream>>>(
          xn, scale, shift, N * DD / 4);
    }
    xc = xn;
    eac = ean;
  }
}